// Round 2
// baseline (30817.398 us; speedup 1.0000x reference)
//
#include <hip/hip_runtime.h>

typedef unsigned short u16;
typedef __attribute__((ext_vector_type(8))) _Float16 half8;
typedef __attribute__((ext_vector_type(4))) float f32x4;

#define MFMA16(a,b,c) __builtin_amdgcn_mfma_f32_16x16x32_f16((a),(b),(c),0,0,0)

#define NWG 96
#define S_LEN 2048
#define HS (64*512)   // elements in one h buffer [64][512]

// ---------- ws layout (bytes) ----------
#define OFF_W0   0            // Whh0 fp16 [2048][512]            2 MB
#define OFF_W1   2097152      // [Wih1|Whh1] fp16 [2048][1024]    4 MB
#define OFF_T0   6291456      // table f32 [16][2048]             128 KB
#define OFF_B1   6422528      // bias1 f32 [2048]                 8 KB
#define OFF_PIDX 6430720      // u16 [2048][64]                   256 KB
#define OFF_H0   6692864      // fp16 2x[64][512]                 128 KB
#define OFF_H1   6823936      // fp16 2x[64][512]                 128 KB
#define OFF_HF   6955008      // f32 [64][512]                    128 KB
#define OFF_BAR  7086080      // int barrier counter

__device__ __forceinline__ u16 f2h(float f) {
  _Float16 h = (_Float16)f;
  return __builtin_bit_cast(u16, h);
}
__device__ __forceinline__ float sigf(float x)   { return 1.f/(1.f + __expf(-x)); }
__device__ __forceinline__ float tanhf_(float x) { return 2.f/(1.f + __expf(-2.f*x)) - 1.f; }

__device__ __forceinline__ void grid_barrier(int* bar) {
  __syncthreads();
  if (threadIdx.x == 0) {
    __threadfence();  // release: drain + write back this XCD's L2
    int a = __hip_atomic_fetch_add(bar, 1, __ATOMIC_RELAXED, __HIP_MEMORY_SCOPE_AGENT);
    int target = (a / NWG + 1) * NWG;
    while (__hip_atomic_load(bar, __ATOMIC_RELAXED, __HIP_MEMORY_SCOPE_AGENT) < target)
      __builtin_amdgcn_s_sleep(1);
    __threadfence();  // acquire: invalidate L1/L2 before reading peers' h
  }
  __syncthreads();
}

// ---------- prep: weight conversion, bias sum, zero h, reset barrier ----------
__global__ void k_prep(const float* __restrict__ Wih, const float* __restrict__ Whh,
                       const float* __restrict__ bih, const float* __restrict__ bhh,
                       u16* __restrict__ W0, u16* __restrict__ W1,
                       float* __restrict__ b1g, u16* __restrict__ hz, int* __restrict__ bar)
{
  int i = blockIdx.x * blockDim.x + threadIdx.x;
  int st = gridDim.x * blockDim.x;
  if (i == 0) bar[0] = 0;
  for (int e = i; e < 2048*512; e += st) W0[e] = f2h(Whh[e]);          // layer0 Whh
  for (int e = i; e < 2048*1024; e += st) {
    int j = e >> 10, k = e & 1023;
    float v = (k < 512) ? Wih[2048*512 + j*512 + k]
                        : Whh[2048*512 + j*512 + (k - 512)];
    W1[e] = f2h(v);
  }
  for (int e = i; e < 2048; e += st) b1g[e] = bih[2048 + e] + bhh[2048 + e];
  for (int e = i; e < 131072; e += st) hz[e] = 0;   // zero h0(2) + h1(2), contiguous
}

// ---------- pidx: pair index per (t,b), with int32/int64 auto-detect ----------
__global__ void k_pidx(const int* __restrict__ inp32, u16* __restrict__ pidx)
{
  __shared__ int is64s;
  if (threadIdx.x == 0) {
    int z = 0;
    for (int t = 0; t < 64; ++t) z |= inp32[2*t + 1];   // high words all zero => int64
    is64s = (z == 0) ? 1 : 0;
  }
  __syncthreads();
  const int is64 = is64s;
  int i = blockIdx.x * blockDim.x + threadIdx.x;
  int st = gridDim.x * blockDim.x;
  for (int e = i; e < S_LEN*64; e += st) {
    int t = e >> 6, b = e & 63;
    int i0 = b * S_LEN + t;
    int i1 = 64 * S_LEN + b * S_LEN + t;
    int a = is64 ? inp32[2*i0] : inp32[i0];
    int c = is64 ? inp32[2*i1] : inp32[i1];
    pidx[e] = (u16)(a * 4 + c);
  }
}

// ---------- table: T0[p][j] = (embed[a]+embed[c]) . Wih0[j] + bih0[j]+bhh0[j] ----------
__global__ void k_table(const float* __restrict__ embed, const float* __restrict__ Wih,
                        const float* __restrict__ bih, const float* __restrict__ bhh,
                        float* __restrict__ T0)
{
  int idx = blockIdx.x * blockDim.x + threadIdx.x;
  if (idx >= 16*2048) return;
  int p = idx >> 11, j = idx & 2047;
  const float* ea = embed + (p >> 2) * 512;
  const float* ec = embed + (p & 3) * 512;
  const float* w  = Wih + j * 512;
  float acc = bih[j] + bhh[j];
  for (int k = 0; k < 512; ++k) acc += (ea[k] + ec[k]) * w[k];
  T0[p * 2048 + j] = acc;
}

// ---------- persistent pipelined 2-layer LSTM ----------
__global__ __launch_bounds__(256, 1) void k_lstm(
    const u16* __restrict__ W0, const u16* __restrict__ W1,
    const float* __restrict__ T0, const float* __restrict__ b1g,
    const u16* __restrict__ pidx,
    u16* __restrict__ h0b, u16* __restrict__ h1b,
    float* __restrict__ hfin, int* __restrict__ bar)
{
  __shared__ float gbuf[64*64];
  __shared__ float cst[16*64];
  const int tid  = threadIdx.x;
  const int lane = tid & 63, wave = tid >> 6;
  const int wg   = blockIdx.x;
  const int mrow = lane & 15, kb = (lane >> 4) * 8;

  for (int e = tid; e < 16*64; e += 256) cst[e] = 0.f;

  if (wg < 32) {
    // ================= layer 0: 16 h-columns, 64 gate rows, K=512 =================
    const int jc = wg * 16;
    half8 wa0[16], wa1_[16], wa2[16], wa3[16];   // weights resident in VGPRs
#pragma unroll
    for (int ks = 0; ks < 16; ++ks) {
      wa0[ks]  = *(const half8*)(W0 + (0*512 + jc + mrow)*512 + ks*32 + kb);
      wa1_[ks] = *(const half8*)(W0 + (1*512 + jc + mrow)*512 + ks*32 + kb);
      wa2[ks]  = *(const half8*)(W0 + (2*512 + jc + mrow)*512 + ks*32 + kb);
      wa3[ks]  = *(const half8*)(W0 + (3*512 + jc + mrow)*512 + ks*32 + kb);
    }
    const int nb = wave*16 + mrow;       // batch row this lane loads (B-frag)
    const int col = wave*16 + mrow;      // C-tile column (batch)
    for (int s = 0; s < S_LEN; ++s) {
      const u16* hr = h0b + ((s+1)&1)*HS;   // h0[s-1]
      u16* hw       = h0b + (s&1)*HS;       // h0[s]
      half8 bf[16];
#pragma unroll
      for (int ks = 0; ks < 16; ++ks)
        bf[ks] = *(const half8*)(hr + nb*512 + ks*32 + kb);
      f32x4 a0 = {0,0,0,0}, a1 = {0,0,0,0}, a2 = {0,0,0,0}, a3 = {0,0,0,0};
#pragma unroll
      for (int ks = 0; ks < 16; ++ks) {
        a0 = MFMA16(wa0[ks],  bf[ks], a0);
        a1 = MFMA16(wa1_[ks], bf[ks], a1);
        a2 = MFMA16(wa2[ks],  bf[ks], a2);
        a3 = MFMA16(wa3[ks],  bf[ks], a3);
      }
      const int rb = (lane >> 4) * 4;
#pragma unroll
      for (int r = 0; r < 4; ++r) {
        gbuf[(0*16 + rb + r)*64 + col] = a0[r];
        gbuf[(1*16 + rb + r)*64 + col] = a1[r];
        gbuf[(2*16 + rb + r)*64 + col] = a2[r];
        gbuf[(3*16 + rb + r)*64 + col] = a3[r];
      }
      __syncthreads();
      {
        const int b  = tid & 63;
        const int jg = tid >> 6;
        const int p  = pidx[s*64 + b];
        const float* t0p = T0 + p*2048 + jc;
#pragma unroll
        for (int it = 0; it < 4; ++it) {
          const int jj = jg + it*4;
          float gi = gbuf[(jj)*64 + b]      + t0p[jj];
          float gf = gbuf[(16+jj)*64 + b]   + t0p[512 + jj];
          float gg = gbuf[(32+jj)*64 + b]   + t0p[1024 + jj];
          float go = gbuf[(48+jj)*64 + b]   + t0p[1536 + jj];
          float c  = cst[jj*64 + b];
          c = sigf(gf)*c + sigf(gi)*tanhf_(gg);
          float h = sigf(go)*tanhf_(c);
          cst[jj*64 + b] = c;
          hw[b*512 + jc + jj] = f2h(h);
        }
      }
      grid_barrier(bar);
    }
    grid_barrier(bar);   // super-step s = S (layer0 idle)
  } else {
    // ============ layer 1: 8 h-columns, 32 gate rows, K=1024 ([h0|h1]) ============
    const int w1 = wg - 32;
    const int jc = w1 * 8;
    const int g0 = (mrow >> 3);
    const int jr = mrow & 7;
    const int r0 = ((0*2 + g0)*512 + jc + jr) * 1024;   // mt=0 global row
    const int r1 = ((1*2 + g0)*512 + jc + jr) * 1024;   // mt=1 global row
    half8 wA[16], wB[16], wA2[16], wB2[16];
#pragma unroll
    for (int ks = 0; ks < 16; ++ks) {
      wA[ks]  = *(const half8*)(W1 + r0 + ks*32 + kb);          // k in [0,512)   (h0)
      wB[ks]  = *(const half8*)(W1 + r0 + 512 + ks*32 + kb);    // k in [512,1024)(h1)
      wA2[ks] = *(const half8*)(W1 + r1 + ks*32 + kb);
      wB2[ks] = *(const half8*)(W1 + r1 + 512 + ks*32 + kb);
    }
    const int nb = wave*16 + mrow;
    const int col = wave*16 + mrow;
    grid_barrier(bar);   // super-step s = 0 (layer1 idle)
    for (int s = 1; s <= S_LEN; ++s) {
      const u16* h0r = h0b + ((s+1)&1)*HS;  // h0[s-1]
      const u16* h1r = h1b + (s&1)*HS;      // h1[s-2]
      u16* h1w       = h1b + ((s+1)&1)*HS;  // h1[s-1]
      half8 bf[16];
#pragma unroll
      for (int ks = 0; ks < 16; ++ks)
        bf[ks] = *(const half8*)(h0r + nb*512 + ks*32 + kb);
      f32x4 a0 = {0,0,0,0}, a1 = {0,0,0,0}, a2 = {0,0,0,0}, a3 = {0,0,0,0};
#pragma unroll
      for (int ks = 0; ks < 16; ++ks) {
        a0 = MFMA16(wA[ks],  bf[ks], a0);
        a1 = MFMA16(wA2[ks], bf[ks], a1);
      }
#pragma unroll
      for (int ks = 0; ks < 16; ++ks)
        bf[ks] = *(const half8*)(h1r + nb*512 + ks*32 + kb);
#pragma unroll
      for (int ks = 0; ks < 16; ++ks) {
        a2 = MFMA16(wB[ks],  bf[ks], a2);
        a3 = MFMA16(wB2[ks], bf[ks], a3);
      }
      const int rb = (lane >> 4) * 4;
#pragma unroll
      for (int r = 0; r < 4; ++r) {
        gbuf[(0*16 + rb + r)*64 + col] = a0[r] + a2[r];
        gbuf[(1*16 + rb + r)*64 + col] = a1[r] + a3[r];
      }
      __syncthreads();
      {
        const int b  = tid & 63;
        const int jg = tid >> 6;
#pragma unroll
        for (int it = 0; it < 2; ++it) {
          const int jj = jg + it*4;   // 0..7
          float gi = gbuf[(0*8 + jj)*64 + b] + b1g[0*512 + jc + jj];
          float gf = gbuf[(1*8 + jj)*64 + b] + b1g[1*512 + jc + jj];
          float gg = gbuf[(2*8 + jj)*64 + b] + b1g[2*512 + jc + jj];
          float go = gbuf[(3*8 + jj)*64 + b] + b1g[3*512 + jc + jj];
          float c  = cst[jj*64 + b];
          c = sigf(gf)*c + sigf(gi)*tanhf_(gg);
          float h = sigf(go)*tanhf_(c);
          cst[jj*64 + b] = c;
          h1w[b*512 + jc + jj] = f2h(h);
          if (s == S_LEN) hfin[b*512 + jc + jj] = h;
        }
      }
      grid_barrier(bar);
    }
  }
}

// ---------- finalize: LayerNorm + projection ----------
__global__ __launch_bounds__(256) void k_final(
    const float* __restrict__ hfin, const float* __restrict__ ln_g,
    const float* __restrict__ ln_b, const float* __restrict__ Wp,
    const float* __restrict__ bp, float* __restrict__ out)
{
  __shared__ float sb[8];
  __shared__ float sred[4];
  const int b = blockIdx.x, tid = threadIdx.x;
  const float* h = hfin + b * 512;
  float v1 = h[tid], v2 = h[tid + 256];
  float s1 = v1 + v2, s2 = v1*v1 + v2*v2;
#pragma unroll
  for (int o = 32; o; o >>= 1) { s1 += __shfl_down(s1, o); s2 += __shfl_down(s2, o); }
  if ((tid & 63) == 0) { sb[tid >> 6] = s1; sb[4 + (tid >> 6)] = s2; }
  __syncthreads();
  float S1 = sb[0] + sb[1] + sb[2] + sb[3];
  float S2 = sb[4] + sb[5] + sb[6] + sb[7];
  float mu = S1 * (1.f/512.f);
  float var = S2 * (1.f/512.f) - mu*mu;
  float inv = rsqrtf(var + 1e-5f);
  float acc = ((v1 - mu)*inv*ln_g[tid]       + ln_b[tid])       * Wp[tid]
            + ((v2 - mu)*inv*ln_g[tid + 256] + ln_b[tid + 256]) * Wp[tid + 256];
#pragma unroll
  for (int o = 32; o; o >>= 1) acc += __shfl_down(acc, o);
  if ((tid & 63) == 0) sred[tid >> 6] = acc;
  __syncthreads();
  if (tid == 0) out[b] = sred[0] + sred[1] + sred[2] + sred[3] + bp[0];
}

extern "C" void kernel_launch(void* const* d_in, const int* in_sizes, int n_in,
                              void* d_out, int out_size, void* d_ws, size_t ws_size,
                              hipStream_t stream) {
  (void)in_sizes; (void)n_in; (void)out_size; (void)ws_size;
  const int*   inp   = (const int*)d_in[0];
  const float* embed = (const float*)d_in[1];
  const float* Wih   = (const float*)d_in[2];
  const float* Whh   = (const float*)d_in[3];
  const float* bih   = (const float*)d_in[4];
  const float* bhh   = (const float*)d_in[5];
  const float* ln_g  = (const float*)d_in[6];
  const float* ln_b  = (const float*)d_in[7];
  const float* Wp    = (const float*)d_in[8];
  const float* bp    = (const float*)d_in[9];
  float* out = (float*)d_out;
  char* ws = (char*)d_ws;

  u16*   W0   = (u16*)  (ws + OFF_W0);
  u16*   W1   = (u16*)  (ws + OFF_W1);
  float* T0   = (float*)(ws + OFF_T0);
  float* b1g  = (float*)(ws + OFF_B1);
  u16*   pidx = (u16*)  (ws + OFF_PIDX);
  u16*   h0   = (u16*)  (ws + OFF_H0);
  u16*   h1   = (u16*)  (ws + OFF_H1);
  float* hfin = (float*)(ws + OFF_HF);
  int*   bar  = (int*)  (ws + OFF_BAR);

  k_prep<<<512, 256, 0, stream>>>(Wih, Whh, bih, bhh, W0, W1, b1g, h0, bar);
  k_pidx<<<64, 256, 0, stream>>>(inp, pidx);
  k_table<<<128, 256, 0, stream>>>(embed, Wih, bih, bhh, T0);

  k_lstm<<<dim3(NWG), dim3(256), 0, stream>>>(W0, W1, T0, b1g, pidx,
                                              h0, h1, hfin, bar);

  k_final<<<64, 256, 0, stream>>>(hfin, ln_g, ln_b, Wp, bp, out);
}

// Round 3
// 28857.953 us; speedup vs baseline: 1.0679x; 1.0679x over previous
//
#include <hip/hip_runtime.h>

typedef unsigned short u16;
typedef unsigned char u8;
typedef unsigned long long u64;
typedef __attribute__((ext_vector_type(8))) _Float16 half8;
typedef __attribute__((ext_vector_type(4))) float f32x4;

#define MFMA16(a,b,c) __builtin_amdgcn_mfma_f32_16x16x32_f16((a),(b),(c),0,0,0)

#define NWG0 64
#define NWG1 64
#define S_LEN 2048
#define HS (64*512)   // u16 elements in one h buffer [64][512]

// ---------- ws layout (bytes) ----------
#define OFF_W0P  0            // fp16 [64 wg][2 tile][16 row][512 k]      2 MB
#define OFF_W1P  2097152      // fp16 [64 wg][2 kh][2 tile][16][512]      4 MB
#define OFF_T0   6291456      // f32 [16 pair][4 gate][512 col]           128 KB
#define OFF_B1   6422528      // f32 [4 gate][512 col]                    8 KB
#define OFF_PIDX 6430720      // u8 [2048][64]                            128 KB
#define OFF_H0   6561792      // fp16 3 x [64][512]                       192 KB
#define OFF_H1   6758400      // fp16 3 x [64][512]                       192 KB
#define OFF_FLAG 6955008      // int flagsA[64], flagsB[64]               512 B

__device__ __forceinline__ u16 f2h(float f) {
  _Float16 h = (_Float16)f;
  return __builtin_bit_cast(u16, h);
}
__device__ __forceinline__ float sigf(float x)   { return 1.f/(1.f + __expf(-x)); }
__device__ __forceinline__ float tanhf_(float x) { return 2.f/(1.f + __expf(-2.f*x)) - 1.f; }

// device-coherent (sc0 sc1) 16B load as two u64 atomic loads
__device__ __forceinline__ half8 load_h8(const u16* p) {
  union { half8 v; u64 q[2]; } u;
  const u64* q = (const u64*)p;
  u.q[0] = __hip_atomic_load(q + 0, __ATOMIC_RELAXED, __HIP_MEMORY_SCOPE_AGENT);
  u.q[1] = __hip_atomic_load(q + 1, __ATOMIC_RELAXED, __HIP_MEMORY_SCOPE_AGENT);
  return u.v;
}
// device-coherent 8B store of 4 fp16
__device__ __forceinline__ void store_h4(u16* p, const float* hv) {
  union { u64 q; _Float16 h[4]; } u;
  u.h[0] = (_Float16)hv[0]; u.h[1] = (_Float16)hv[1];
  u.h[2] = (_Float16)hv[2]; u.h[3] = (_Float16)hv[3];
  __hip_atomic_store((u64*)p, u.q, __ATOMIC_RELAXED, __HIP_MEMORY_SCOPE_AGENT);
}

__device__ __forceinline__ void poll_flags(const int* fA, const int* fB,
                                           int lane, int nA, int nB) {
  for (;;) {
    int a = __hip_atomic_load(fA + lane, __ATOMIC_RELAXED, __HIP_MEMORY_SCOPE_AGENT);
    int b = __hip_atomic_load(fB + lane, __ATOMIC_RELAXED, __HIP_MEMORY_SCOPE_AGENT);
    if (__all(a >= nA && b >= nB)) break;
  }
  asm volatile("" ::: "memory");
}

// ---------- prep: weight permute+convert, bias sum, zero h, reset flags ----------
__global__ void k_prep(const float* __restrict__ Wih, const float* __restrict__ Whh,
                       const float* __restrict__ bih, const float* __restrict__ bhh,
                       u16* __restrict__ W0p, u16* __restrict__ W1p,
                       float* __restrict__ b1, u16* __restrict__ hz, int* __restrict__ flags)
{
  int i = blockIdx.x * blockDim.x + threadIdx.x;
  int st = gridDim.x * blockDim.x;
  // W0p[wg][tile][row][k]: tile t, row r -> gate = t*2+(r>>3), col = wg*8+(r&7); src layer0 Whh
  for (int e = i; e < 64*2*16*512; e += st) {
    int k = e & 511, row = (e >> 9) & 15, tile = (e >> 13) & 1, wg = e >> 14;
    int gate = tile*2 + (row >> 3);
    int col  = wg*8 + (row & 7);
    W0p[e] = f2h(Whh[(gate*512 + col)*512 + k]);
  }
  // W1p[wg][kh][tile][row][k]: kh=0 -> Wih layer1 (h0 input), kh=1 -> Whh layer1
  for (int e = i; e < 64*2*2*16*512; e += st) {
    int k = e & 511, row = (e >> 9) & 15, tile = (e >> 13) & 1, kh = (e >> 14) & 1, wg = e >> 15;
    int gate = tile*2 + (row >> 3);
    int col  = wg*8 + (row & 7);
    const float* src = kh ? Whh : Wih;
    W1p[e] = f2h(src[2048*512 + (gate*512 + col)*512 + k]);
  }
  for (int e = i; e < 4*512; e += st) b1[e] = bih[2048 + e] + bhh[2048 + e];
  for (int e = i; e < 6*HS; e += st) hz[e] = 0;   // zero h0(3 bufs) + h1(3 bufs)
  for (int e = i; e < 128; e += st) flags[e] = 0;
}

// ---------- pidx: pair index per (t,b), int32/int64 auto-detect ----------
__global__ void k_pidx(const int* __restrict__ inp32, u8* __restrict__ pidx)
{
  __shared__ int is64s;
  if (threadIdx.x == 0) {
    int z = 0;
    for (int t = 0; t < 64; ++t) z |= inp32[2*t + 1];
    is64s = (z == 0) ? 1 : 0;
  }
  __syncthreads();
  const int is64 = is64s;
  int i = blockIdx.x * blockDim.x + threadIdx.x;
  int st = gridDim.x * blockDim.x;
  for (int e = i; e < S_LEN*64; e += st) {
    int t = e >> 6, b = e & 63;
    int i0 = b * S_LEN + t;
    int i1 = 64 * S_LEN + b * S_LEN + t;
    int a = is64 ? inp32[2*i0] : inp32[i0];
    int c = is64 ? inp32[2*i1] : inp32[i1];
    pidx[e] = (u8)(a * 4 + c);
  }
}

// ---------- table: T0[p][g][j] = (embed[a]+embed[c]) . Wih0[g*512+j] + bias0 ----------
__global__ void k_table(const float* __restrict__ embed, const float* __restrict__ Wih,
                        const float* __restrict__ bih, const float* __restrict__ bhh,
                        float* __restrict__ T0)
{
  int idx = blockIdx.x * blockDim.x + threadIdx.x;
  if (idx >= 16*2048) return;
  int p = idx >> 11, gj = idx & 2047;   // gj = gate*512 + col = Wih0 row
  const float* ea = embed + (p >> 2) * 512;
  const float* ec = embed + (p & 3) * 512;
  const float* w  = Wih + gj * 512;
  float acc = bih[gj] + bhh[gj];
  for (int k = 0; k < 512; ++k) acc += (ea[k] + ec[k]) * w[k];
  T0[p * 2048 + gj] = acc;
}

// ---------- persistent pipelined 2-layer LSTM, flag-synced ----------
__global__ __launch_bounds__(256, 1) void k_lstm(
    const u16* __restrict__ W0p, const u16* __restrict__ W1p,
    const float* __restrict__ T0, const float* __restrict__ b1,
    const u8* __restrict__ pidx,
    u16* __restrict__ h0b, u16* __restrict__ h1b, int* __restrict__ flags)
{
  __shared__ float xbuf[2*4*64*4];   // [bh][tile q][lane][4] partial-acc exchange (layer1)
  const int tid  = threadIdx.x;
  const int lane = tid & 63, wave = tid >> 6;
  const int wg   = blockIdx.x;
  const int mrow = lane & 15, kb = (lane >> 4) * 8;
  const int rb   = ((lane >> 4) * 4) & 7;   // 0/4 for lanes<32 (and harmless alias above)
  int* fA = flags;
  int* fB = flags + 64;

  if (wg < NWG0) {
    // ============ layer 0: 8 cols, gates (i,f) tile0 / (g,o) tile1, K=512 ============
    const int jc = wg * 8;
    const u16* wb = W0p + wg * 16384;
    half8 wa0[16], wa1[16];
#pragma unroll
    for (int ks = 0; ks < 16; ++ks) {
      wa0[ks] = *(const half8*)(wb +        mrow*512 + ks*32 + kb);
      wa1[ks] = *(const half8*)(wb + 8192 + mrow*512 + ks*32 + kb);
    }
#pragma unroll
    for (int ks = 0; ks < 16; ++ks)
      asm volatile("" : "+v"(wa0[ks]), "+v"(wa1[ks]));   // pin weights in VGPRs
    const int b = wave*16 + mrow;
    float cs[4] = {0.f, 0.f, 0.f, 0.f};
    for (int t = 0; t < S_LEN; ++t) {
      poll_flags(fA, fB, lane, t, t - 2);
      const u16* hr = h0b + ((t + 2) % 3) * HS;   // h0[t-1]
      u16*       hw = h0b + (t % 3) * HS;         // h0[t]
      half8 bf[16];
#pragma unroll
      for (int ks = 0; ks < 16; ++ks)
        bf[ks] = load_h8(hr + b*512 + ks*32 + kb);
      f32x4 a0 = {0,0,0,0}, a1 = {0,0,0,0};
#pragma unroll
      for (int ks = 0; ks < 16; ++ks) {
        a0 = MFMA16(wa0[ks], bf[ks], a0);
        a1 = MFMA16(wa1[ks], bf[ks], a1);
      }
      f32x4 fsh, osh;
#pragma unroll
      for (int r = 0; r < 4; ++r) {
        fsh[r] = __shfl_xor(a0[r], 32);
        osh[r] = __shfl_xor(a1[r], 32);
      }
      if (lane < 32) {
        const int p = pidx[t*64 + b];
        const float* tp = T0 + p*2048 + jc + rb;
        float hv[4];
#pragma unroll
        for (int r = 0; r < 4; ++r) {
          float gi = a0[r]  + tp[0*512 + r];
          float gf = fsh[r] + tp[1*512 + r];
          float gg = a1[r]  + tp[2*512 + r];
          float go = osh[r] + tp[3*512 + r];
          float cc = sigf(gf)*cs[r] + sigf(gi)*tanhf_(gg);
          cs[r] = cc;
          hv[r] = sigf(go)*tanhf_(cc);
        }
        store_h4(hw + b*512 + jc + rb, hv);
      }
      asm volatile("s_waitcnt vmcnt(0)" ::: "memory");
      __syncthreads();
      if (tid == 0)
        __hip_atomic_store(fA + wg, t + 1, __ATOMIC_RELAXED, __HIP_MEMORY_SCOPE_AGENT);
    }
  } else {
    // ====== layer 1: 8 cols, K=1024 split kh=0(h0)/kh=1(h1) across wave pairs ======
    const int w1 = wg - NWG0, jc = w1 * 8;
    const int kh = wave & 1, bh = wave >> 1;
    const u16* wb = W1p + (w1*2 + kh) * 16384;
    half8 wa0[16], wa1[16];
#pragma unroll
    for (int ks = 0; ks < 16; ++ks) {
      wa0[ks] = *(const half8*)(wb +        mrow*512 + ks*32 + kb);
      wa1[ks] = *(const half8*)(wb + 8192 + mrow*512 + ks*32 + kb);
    }
#pragma unroll
    for (int ks = 0; ks < 16; ++ks)
      asm volatile("" : "+v"(wa0[ks]), "+v"(wa1[ks]));
    float bi[4][4];
    if (lane < 32) {
#pragma unroll
      for (int g = 0; g < 4; ++g)
#pragma unroll
        for (int r = 0; r < 4; ++r)
          bi[g][r] = b1[g*512 + jc + rb + r];
    }
    float cs[2][4] = {{0,0,0,0},{0,0,0,0}};
    for (int w = 1; w <= S_LEN; ++w) {
      const int u = w - 1;            // computing h1[u]
      poll_flags(fA, fB, lane, w, w - 1);
      const u16* src = (kh == 0) ? (h0b + (u % 3) * HS)          // h0[u]
                                 : (h1b + ((u + 2) % 3) * HS);   // h1[u-1]
      u16* hw = h1b + (u % 3) * HS;                              // h1[u]
      f32x4 acc[2][2] = {{{0,0,0,0},{0,0,0,0}},{{0,0,0,0},{0,0,0,0}}};
#pragma unroll
      for (int nt = 0; nt < 2; ++nt) {
        const int nb = bh*32 + nt*16 + mrow;
        half8 bf[16];
#pragma unroll
        for (int ks = 0; ks < 16; ++ks)
          bf[ks] = load_h8(src + nb*512 + ks*32 + kb);
#pragma unroll
        for (int ks = 0; ks < 16; ++ks) {
          acc[nt][0] = MFMA16(wa0[ks], bf[ks], acc[nt][0]);
          acc[nt][1] = MFMA16(wa1[ks], bf[ks], acc[nt][1]);
        }
      }
      if (kh == 1) {
#pragma unroll
        for (int q = 0; q < 4; ++q)
          *(f32x4*)(xbuf + ((bh*4 + q)*64 + lane)*4) = acc[q >> 1][q & 1];
      }
      __syncthreads();
      if (kh == 0) {
#pragma unroll
        for (int q = 0; q < 4; ++q)
          acc[q >> 1][q & 1] += *(const f32x4*)(xbuf + ((bh*4 + q)*64 + lane)*4);
#pragma unroll
        for (int nt = 0; nt < 2; ++nt) {
          f32x4 fsh, osh;
#pragma unroll
          for (int r = 0; r < 4; ++r) {
            fsh[r] = __shfl_xor(acc[nt][0][r], 32);
            osh[r] = __shfl_xor(acc[nt][1][r], 32);
          }
          if (lane < 32) {
            const int nb = bh*32 + nt*16 + mrow;
            float hv[4];
#pragma unroll
            for (int r = 0; r < 4; ++r) {
              float gi = acc[nt][0][r] + bi[0][r];
              float gf = fsh[r]        + bi[1][r];
              float gg = acc[nt][1][r] + bi[2][r];
              float go = osh[r]        + bi[3][r];
              float cc = sigf(gf)*cs[nt][r] + sigf(gi)*tanhf_(gg);
              cs[nt][r] = cc;
              hv[r] = sigf(go)*tanhf_(cc);
            }
            store_h4(hw + nb*512 + jc + rb, hv);
          }
        }
      }
      asm volatile("s_waitcnt vmcnt(0)" ::: "memory");
      __syncthreads();
      if (tid == 0)
        __hip_atomic_store(fB + w1, w, __ATOMIC_RELAXED, __HIP_MEMORY_SCOPE_AGENT);
    }
  }
}

// ---------- finalize: LayerNorm + projection from h1[2047] (fp16, buf 1) ----------
__global__ __launch_bounds__(256) void k_final(
    const u16* __restrict__ h1last, const float* __restrict__ ln_g,
    const float* __restrict__ ln_b, const float* __restrict__ Wp,
    const float* __restrict__ bp, float* __restrict__ out)
{
  __shared__ float sb[8];
  __shared__ float sred[4];
  const int b = blockIdx.x, tid = threadIdx.x;
  const _Float16* h = (const _Float16*)(h1last) + b * 512;
  float v1 = (float)h[tid], v2 = (float)h[tid + 256];
  float s1 = v1 + v2, s2 = v1*v1 + v2*v2;
#pragma unroll
  for (int o = 32; o; o >>= 1) { s1 += __shfl_down(s1, o); s2 += __shfl_down(s2, o); }
  if ((tid & 63) == 0) { sb[tid >> 6] = s1; sb[4 + (tid >> 6)] = s2; }
  __syncthreads();
  float S1 = sb[0] + sb[1] + sb[2] + sb[3];
  float S2 = sb[4] + sb[5] + sb[6] + sb[7];
  float mu = S1 * (1.f/512.f);
  float var = S2 * (1.f/512.f) - mu*mu;
  float inv = rsqrtf(var + 1e-5f);
  float acc = ((v1 - mu)*inv*ln_g[tid]       + ln_b[tid])       * Wp[tid]
            + ((v2 - mu)*inv*ln_g[tid + 256] + ln_b[tid + 256]) * Wp[tid + 256];
#pragma unroll
  for (int o = 32; o; o >>= 1) acc += __shfl_down(acc, o);
  if ((tid & 63) == 0) sred[tid >> 6] = acc;
  __syncthreads();
  if (tid == 0) out[b] = sred[0] + sred[1] + sred[2] + sred[3] + bp[0];
}

extern "C" void kernel_launch(void* const* d_in, const int* in_sizes, int n_in,
                              void* d_out, int out_size, void* d_ws, size_t ws_size,
                              hipStream_t stream) {
  (void)in_sizes; (void)n_in; (void)out_size; (void)ws_size;
  const int*   inp   = (const int*)d_in[0];
  const float* embed = (const float*)d_in[1];
  const float* Wih   = (const float*)d_in[2];
  const float* Whh   = (const float*)d_in[3];
  const float* bih   = (const float*)d_in[4];
  const float* bhh   = (const float*)d_in[5];
  const float* ln_g  = (const float*)d_in[6];
  const float* ln_b  = (const float*)d_in[7];
  const float* Wp    = (const float*)d_in[8];
  const float* bp    = (const float*)d_in[9];
  float* out = (float*)d_out;
  char* ws = (char*)d_ws;

  u16*   W0p  = (u16*)  (ws + OFF_W0P);
  u16*   W1p  = (u16*)  (ws + OFF_W1P);
  float* T0   = (float*)(ws + OFF_T0);
  float* b1   = (float*)(ws + OFF_B1);
  u8*    pidx = (u8*)   (ws + OFF_PIDX);
  u16*   h0   = (u16*)  (ws + OFF_H0);
  u16*   h1   = (u16*)  (ws + OFF_H1);
  int*   flags= (int*)  (ws + OFF_FLAG);

  k_prep<<<512, 256, 0, stream>>>(Wih, Whh, bih, bhh, W0p, W1p, b1, h0, flags);
  k_pidx<<<64, 256, 0, stream>>>(inp, pidx);
  k_table<<<128, 256, 0, stream>>>(embed, Wih, bih, bhh, T0);

  k_lstm<<<dim3(NWG0 + NWG1), dim3(256), 0, stream>>>(W0p, W1p, T0, b1, pidx,
                                                      h0, h1, flags);

  // h1[2047] lives in buffer (2047 % 3) == 1
  k_final<<<64, 256, 0, stream>>>(h1 + 1*HS, ln_g, ln_b, Wp, bp, out);
}

// Round 4
// 14127.428 us; speedup vs baseline: 2.1814x; 2.0427x over previous
//
#include <hip/hip_runtime.h>

typedef unsigned short u16;
typedef unsigned char u8;
typedef unsigned long long u64;
typedef __attribute__((ext_vector_type(8))) _Float16 half8;
typedef __attribute__((ext_vector_type(4))) float f32x4;

#define MFMA16(a,b,c) __builtin_amdgcn_mfma_f32_16x16x32_f16((a),(b),(c),0,0,0)

#define S_LEN 2048
#define HS (64*512)    // u16 elements per h buffer [64][512]
#define NB0 4          // h0 ring buffers
#define NB1 4          // h1 ring buffers
#define NGRP 4         // independent batch groups (16 batch rows each)

// ---------- ws layout (bytes) ----------
#define OFF_W0P  0            // fp16 [8 wgi][4 wv][4 g][16 m][512 k]   2 MB
#define OFF_W1P  2097152      // fp16 [16 wgi][2 ch][2 kh][4 g][16][512] 4 MB
#define OFF_T0   6291456      // f32 [16 pair][4 gate][512 col]         128 KB
#define OFF_B1   6422528      // f32 [4 gate][512 col]                  8 KB
#define OFF_PIDX 6430720      // u8 [2048][64]                          128 KB
#define OFF_H0   6561792      // fp16 4 x [64][512]                     256 KB
#define OFF_H1   6823936      // fp16 4 x [64][512]                     256 KB
#define OFF_FLAG 7086080      // int [4 grp][32]: fA[0..7], fB[16..31]

__device__ __forceinline__ u16 f2h(float f) {
  _Float16 h = (_Float16)f;
  return __builtin_bit_cast(u16, h);
}
__device__ __forceinline__ float sigf(float x)   { return 1.f/(1.f + __expf(-x)); }
__device__ __forceinline__ float tanhf_(float x) { return 2.f/(1.f + __expf(-2.f*x)) - 1.f; }

// device-coherent 16B load (two u64 agent-scope atomic loads)
__device__ __forceinline__ half8 load_h8(const u16* p) {
  union { half8 v; u64 q[2]; } u;
  const u64* q = (const u64*)p;
  u.q[0] = __hip_atomic_load(q + 0, __ATOMIC_RELAXED, __HIP_MEMORY_SCOPE_AGENT);
  u.q[1] = __hip_atomic_load(q + 1, __ATOMIC_RELAXED, __HIP_MEMORY_SCOPE_AGENT);
  return u.v;
}
// device-coherent 8B store of 4 fp16
__device__ __forceinline__ void store_h4(u16* p, const float* hv) {
  union { u64 q; _Float16 h[4]; } u;
  u.h[0] = (_Float16)hv[0]; u.h[1] = (_Float16)hv[1];
  u.h[2] = (_Float16)hv[2]; u.h[3] = (_Float16)hv[3];
  __hip_atomic_store((u64*)p, u.q, __ATOMIC_RELAXED, __HIP_MEMORY_SCOPE_AGENT);
}

// group-local poll: lanes 0..15 check fA[lane&7] >= nA, lanes 16..31 fB[lane-16] >= nB
__device__ __forceinline__ void poll(const int* fgrp, int lane, int nA, int nB) {
  const int idx = lane & 31;
  const int* p = fgrp + ((idx < 16) ? (idx & 7) : idx);
  const int need = (idx < 16) ? nA : nB;
  for (;;) {
    int v = __hip_atomic_load(p, __ATOMIC_RELAXED, __HIP_MEMORY_SCOPE_AGENT);
    if (__all(v >= need)) break;
  }
  asm volatile("" ::: "memory");
}

// ---------- prep: weight permute+convert, bias sum, zero h, reset flags ----------
__global__ void k_prep(const float* __restrict__ Wih, const float* __restrict__ Whh,
                       const float* __restrict__ bih, const float* __restrict__ bhh,
                       u16* __restrict__ W0p, u16* __restrict__ W1p,
                       float* __restrict__ b1, u16* __restrict__ hz, int* __restrict__ flags)
{
  int i = blockIdx.x * blockDim.x + threadIdx.x;
  int st = gridDim.x * blockDim.x;
  // W0p[wgi][wv][g][m][k] <- Whh0[g*512 + (wgi*4+wv)*16 + m][k]
  for (int e = i; e < 8*4*4*16*512; e += st) {
    int k = e & 511, m = (e >> 9) & 15, g = (e >> 13) & 3, wv = (e >> 15) & 3, wgi = e >> 17;
    int row = g*512 + (wgi*4 + wv)*16 + m;
    W0p[e] = f2h(Whh[row*512 + k]);
  }
  // W1p[wgi][ch][kh][g][m][k] <- (kh?Whh1:Wih1)[g*512 + wgi*32 + ch*16 + m][k]
  for (int e = i; e < 16*2*2*4*16*512; e += st) {
    int k = e & 511, m = (e >> 9) & 15, g = (e >> 13) & 3, kh = (e >> 15) & 1,
        ch = (e >> 16) & 1, wgi = e >> 17;
    int row = g*512 + wgi*32 + ch*16 + m;
    const float* src = kh ? Whh : Wih;
    W1p[e] = f2h(src[2048*512 + row*512 + k]);
  }
  for (int e = i; e < 4*512; e += st) b1[e] = bih[2048 + e] + bhh[2048 + e];
  for (int e = i; e < (NB0 + NB1)*HS; e += st) hz[e] = 0;  // h0 bufs + h1 bufs contiguous
  for (int e = i; e < NGRP*32; e += st) flags[e] = 0;
}

// ---------- pidx: pair index per (t,b), int32/int64 auto-detect ----------
__global__ void k_pidx(const int* __restrict__ inp32, u8* __restrict__ pidx)
{
  __shared__ int is64s;
  if (threadIdx.x == 0) {
    int z = 0;
    for (int t = 0; t < 64; ++t) z |= inp32[2*t + 1];
    is64s = (z == 0) ? 1 : 0;
  }
  __syncthreads();
  const int is64 = is64s;
  int i = blockIdx.x * blockDim.x + threadIdx.x;
  int st = gridDim.x * blockDim.x;
  for (int e = i; e < S_LEN*64; e += st) {
    int t = e >> 6, b = e & 63;
    int i0 = b * S_LEN + t;
    int i1 = 64 * S_LEN + b * S_LEN + t;
    int a = is64 ? inp32[2*i0] : inp32[i0];
    int c = is64 ? inp32[2*i1] : inp32[i1];
    pidx[e] = (u8)(a * 4 + c);
  }
}

// ---------- table: T0[p][g*512+j] = (embed[a]+embed[c]) . Wih0[g*512+j] + bias0 ----------
__global__ void k_table(const float* __restrict__ embed, const float* __restrict__ Wih,
                        const float* __restrict__ bih, const float* __restrict__ bhh,
                        float* __restrict__ T0)
{
  int idx = blockIdx.x * blockDim.x + threadIdx.x;
  if (idx >= 16*2048) return;
  int p = idx >> 11, gj = idx & 2047;
  const float* ea = embed + (p >> 2) * 512;
  const float* ec = embed + (p & 3) * 512;
  const float* w  = Wih + gj * 512;
  float acc = bih[gj] + bhh[gj];
  for (int k = 0; k < 512; ++k) acc += (ea[k] + ec[k]) * w[k];
  T0[p * 2048 + gj] = acc;
}

// ---------- persistent 2-layer LSTM: 4 independent batch groups, flag-synced ----------
__global__ __launch_bounds__(256, 1) void k_lstm(
    const u16* __restrict__ W0p, const u16* __restrict__ W1p,
    const float* __restrict__ T0, const float* __restrict__ b1,
    const u8* __restrict__ pidx,
    u16* __restrict__ h0b, u16* __restrict__ h1b, int* __restrict__ flags)
{
  __shared__ f32x4 xbuf[2*4*64];   // [ch][g][lane] partial-sum exchange (layer1)
  const int tid  = threadIdx.x;
  const int lane = tid & 63, wave = tid >> 6;
  const int wg   = blockIdx.x;
  const int mrow = lane & 15, kb = (lane >> 4) * 8;
  const int m4   = (lane >> 4) * 4;

  if (wg < 32) {
    // ===== layer 0: group grp, 16 batch rows; wave owns 16 cols x 4 gates, K=512 =====
    const int grp = wg >> 3, wgi = wg & 7;
    int* fgrp = flags + grp*32;
    const int jc = (wgi*4 + wave) * 16;
    const u16* wbase = W0p + (wgi*4 + wave) * 32768;
    half8 wa[4][16];
#pragma unroll
    for (int g = 0; g < 4; ++g)
#pragma unroll
      for (int ks = 0; ks < 16; ++ks)
        wa[g][ks] = *(const half8*)(wbase + (g*16 + mrow)*512 + ks*32 + kb);
    const int bg = grp*16 + mrow;   // global batch row
    float cs[4] = {0.f, 0.f, 0.f, 0.f};
    for (int t = 0; t < S_LEN; ++t) {
      if (wave == 0) poll(fgrp, lane, t, t - (NB0 - 1));
      __syncthreads();
      const u16* hr = h0b + ((t + NB0 - 1) % NB0) * HS;   // h0[t-1]
      u16*       hw = h0b + (t % NB0) * HS;               // h0[t]
      half8 bf[16];
#pragma unroll
      for (int ks = 0; ks < 16; ++ks)
        bf[ks] = load_h8(hr + bg*512 + ks*32 + kb);
      f32x4 acc[4] = {{0,0,0,0},{0,0,0,0},{0,0,0,0},{0,0,0,0}};
#pragma unroll
      for (int ks = 0; ks < 16; ++ks)
#pragma unroll
        for (int g = 0; g < 4; ++g)
          acc[g] = MFMA16(wa[g][ks], bf[ks], acc[g]);
      const int p = pidx[t*64 + bg];
      const float* tp = T0 + p*2048 + jc + m4;
      f32x4 tg[4];
#pragma unroll
      for (int g = 0; g < 4; ++g) tg[g] = *(const f32x4*)(tp + g*512);
      float hv[4];
#pragma unroll
      for (int r = 0; r < 4; ++r) {
        float gi = acc[0][r] + tg[0][r];
        float gf = acc[1][r] + tg[1][r];
        float gg = acc[2][r] + tg[2][r];
        float go = acc[3][r] + tg[3][r];
        float cc = sigf(gf)*cs[r] + sigf(gi)*tanhf_(gg);
        cs[r] = cc;
        hv[r] = sigf(go)*tanhf_(cc);
      }
      store_h4(hw + bg*512 + jc + m4, hv);
      asm volatile("s_waitcnt vmcnt(0)" ::: "memory");
      __syncthreads();
      if (tid == 0)
        __hip_atomic_store(fgrp + wgi, t + 1, __ATOMIC_RELAXED, __HIP_MEMORY_SCOPE_AGENT);
      // loop-carried pin: weights cannot be rematerialized from memory
#pragma unroll
      for (int g = 0; g < 4; ++g)
#pragma unroll
        for (int ks = 0; ks < 16; ++ks)
          asm volatile("" : "+v"(wa[g][ks]));
    }
  } else {
    // ===== layer 1: wave = (ch, kh); 16 cols x 4 gates, K-half 512 (kh0:h0, kh1:h1) =====
    const int w1 = wg - 32;
    const int grp = w1 >> 4, wgi = w1 & 15;
    int* fgrp = flags + grp*32;
    const int kh = wave & 1, ch = wave >> 1;
    const int jc = wgi*32 + ch*16;
    const u16* wbase = W1p + ((wgi*2 + ch)*2 + kh) * 32768;
    half8 wa[4][16];
#pragma unroll
    for (int g = 0; g < 4; ++g)
#pragma unroll
      for (int ks = 0; ks < 16; ++ks)
        wa[g][ks] = *(const half8*)(wbase + (g*16 + mrow)*512 + ks*32 + kb);
    const int bg = grp*16 + mrow;
    f32x4 big[4];
#pragma unroll
    for (int g = 0; g < 4; ++g) big[g] = *(const f32x4*)(b1 + g*512 + jc + m4);
    float cs[4] = {0.f, 0.f, 0.f, 0.f};
    for (int w = 1; w <= S_LEN; ++w) {
      const int u = w - 1;   // computing h1[u]
      if (wave == 0) poll(fgrp, lane, w, w - 1);
      __syncthreads();
      const u16* src = (kh == 0) ? (h0b + (u % NB0) * HS)               // h0[u]
                                 : (h1b + ((u + NB1 - 1) % NB1) * HS);  // h1[u-1]
      u16* hw = h1b + (u % NB1) * HS;                                   // h1[u]
      half8 bf[16];
#pragma unroll
      for (int ks = 0; ks < 16; ++ks)
        bf[ks] = load_h8(src + bg*512 + ks*32 + kb);
      f32x4 acc[4] = {{0,0,0,0},{0,0,0,0},{0,0,0,0},{0,0,0,0}};
#pragma unroll
      for (int ks = 0; ks < 16; ++ks)
#pragma unroll
        for (int g = 0; g < 4; ++g)
          acc[g] = MFMA16(wa[g][ks], bf[ks], acc[g]);
      if (kh == 1) {
#pragma unroll
        for (int g = 0; g < 4; ++g)
          xbuf[(ch*4 + g)*64 + lane] = acc[g];
      }
      __syncthreads();
      if (kh == 0) {
#pragma unroll
        for (int g = 0; g < 4; ++g)
          acc[g] += xbuf[(ch*4 + g)*64 + lane];
        float hv[4];
#pragma unroll
        for (int r = 0; r < 4; ++r) {
          float gi = acc[0][r] + big[0][r];
          float gf = acc[1][r] + big[1][r];
          float gg = acc[2][r] + big[2][r];
          float go = acc[3][r] + big[3][r];
          float cc = sigf(gf)*cs[r] + sigf(gi)*tanhf_(gg);
          cs[r] = cc;
          hv[r] = sigf(go)*tanhf_(cc);
        }
        store_h4(hw + bg*512 + jc + m4, hv);
      }
      asm volatile("s_waitcnt vmcnt(0)" ::: "memory");
      __syncthreads();
      if (tid == 0)
        __hip_atomic_store(fgrp + 16 + wgi, w, __ATOMIC_RELAXED, __HIP_MEMORY_SCOPE_AGENT);
#pragma unroll
      for (int g = 0; g < 4; ++g)
#pragma unroll
        for (int ks = 0; ks < 16; ++ks)
          asm volatile("" : "+v"(wa[g][ks]));
    }
  }
}

// ---------- finalize: LayerNorm + projection from h1[2047] (fp16) ----------
__global__ __launch_bounds__(256) void k_final(
    const u16* __restrict__ h1last, const float* __restrict__ ln_g,
    const float* __restrict__ ln_b, const float* __restrict__ Wp,
    const float* __restrict__ bp, float* __restrict__ out)
{
  __shared__ float sb[8];
  __shared__ float sred[4];
  const int b = blockIdx.x, tid = threadIdx.x;
  const _Float16* h = (const _Float16*)(h1last) + b * 512;
  float v1 = (float)h[tid], v2 = (float)h[tid + 256];
  float s1 = v1 + v2, s2 = v1*v1 + v2*v2;
#pragma unroll
  for (int o = 32; o; o >>= 1) { s1 += __shfl_down(s1, o); s2 += __shfl_down(s2, o); }
  if ((tid & 63) == 0) { sb[tid >> 6] = s1; sb[4 + (tid >> 6)] = s2; }
  __syncthreads();
  float S1 = sb[0] + sb[1] + sb[2] + sb[3];
  float S2 = sb[4] + sb[5] + sb[6] + sb[7];
  float mu = S1 * (1.f/512.f);
  float var = S2 * (1.f/512.f) - mu*mu;
  float inv = rsqrtf(var + 1e-5f);
  float acc = ((v1 - mu)*inv*ln_g[tid]       + ln_b[tid])       * Wp[tid]
            + ((v2 - mu)*inv*ln_g[tid + 256] + ln_b[tid + 256]) * Wp[tid + 256];
#pragma unroll
  for (int o = 32; o; o >>= 1) acc += __shfl_down(acc, o);
  if ((tid & 63) == 0) sred[tid >> 6] = acc;
  __syncthreads();
  if (tid == 0) out[b] = sred[0] + sred[1] + sred[2] + sred[3] + bp[0];
}

extern "C" void kernel_launch(void* const* d_in, const int* in_sizes, int n_in,
                              void* d_out, int out_size, void* d_ws, size_t ws_size,
                              hipStream_t stream) {
  (void)in_sizes; (void)n_in; (void)out_size; (void)ws_size;
  const int*   inp   = (const int*)d_in[0];
  const float* embed = (const float*)d_in[1];
  const float* Wih   = (const float*)d_in[2];
  const float* Whh   = (const float*)d_in[3];
  const float* bih   = (const float*)d_in[4];
  const float* bhh   = (const float*)d_in[5];
  const float* ln_g  = (const float*)d_in[6];
  const float* ln_b  = (const float*)d_in[7];
  const float* Wp    = (const float*)d_in[8];
  const float* bp    = (const float*)d_in[9];
  float* out = (float*)d_out;
  char* ws = (char*)d_ws;

  u16*   W0p  = (u16*)  (ws + OFF_W0P);
  u16*   W1p  = (u16*)  (ws + OFF_W1P);
  float* T0   = (float*)(ws + OFF_T0);
  float* b1   = (float*)(ws + OFF_B1);
  u8*    pidx = (u8*)   (ws + OFF_PIDX);
  u16*   h0   = (u16*)  (ws + OFF_H0);
  u16*   h1   = (u16*)  (ws + OFF_H1);
  int*   flags= (int*)  (ws + OFF_FLAG);

  k_prep<<<512, 256, 0, stream>>>(Wih, Whh, bih, bhh, W0p, W1p, b1, h0, flags);
  k_pidx<<<64, 256, 0, stream>>>(inp, pidx);
  k_table<<<128, 256, 0, stream>>>(embed, Wih, bih, bhh, T0);

  k_lstm<<<dim3(96), dim3(256), 0, stream>>>(W0p, W1p, T0, b1, pidx, h0, h1, flags);

  // h1[2047] lives in buffer (2047 % 4) == 3
  k_final<<<64, 256, 0, stream>>>(h1 + 3*HS, ln_g, ln_b, Wp, bp, out);
}

// Round 5
// 12681.774 us; speedup vs baseline: 2.4301x; 1.1140x over previous
//
#include <hip/hip_runtime.h>

typedef unsigned short u16;
typedef unsigned char u8;
typedef unsigned long long u64;
typedef __attribute__((ext_vector_type(8))) _Float16 half8;
typedef __attribute__((ext_vector_type(4))) float f32x4;
typedef __attribute__((ext_vector_type(4))) unsigned int u32x4;

#define MFMA16(a,b,c) __builtin_amdgcn_mfma_f32_16x16x32_f16((a),(b),(c),0,0,0)

#define S_LEN 2048
#define HS (64*512)    // u16 elements per h buffer [64][512]
#define NB0 4          // h0 ring buffers
#define NB1 4          // h1 ring buffers
#define NGRP 4         // independent batch groups (16 batch rows each)

// ---------- ws layout (bytes) ----------
#define OFF_W0P  0            // fp16 [8 wgi][4 wv][4 g][16 m][512 k]   2 MB
#define OFF_W1P  2097152      // fp16 [16 wgi][2 ch][2 kh][4 g][16][512] 4 MB
#define OFF_T0   6291456      // f32 [16 pair][4 gate][512 col]         128 KB
#define OFF_B1   6422528      // f32 [4 gate][512 col]                  8 KB
#define OFF_PIDX 6430720      // u8 [2048][64]                          128 KB
#define OFF_H0   6561792      // fp16 4 x [64][512]                     256 KB
#define OFF_H1   6823936      // fp16 4 x [64][512]                     256 KB
#define OFF_FLAG 7086080      // int [4 grp][32]: fA[0..7], fB[16..31]

__device__ __forceinline__ u16 f2h(float f) {
  _Float16 h = (_Float16)f;
  return __builtin_bit_cast(u16, h);
}
__device__ __forceinline__ float sigf(float x)   { return 1.f/(1.f + __expf(-x)); }
__device__ __forceinline__ float tanhf_(float x) { return 2.f/(1.f + __expf(-2.f*x)) - 1.f; }

// device-coherent 16B load (bypass L1/L2, read at L3 coherence point)
__device__ __forceinline__ u32x4 gload16(const void* p) {
  u32x4 d;
  asm volatile("global_load_dwordx4 %0, %1, off sc0 sc1"
               : "=&v"(d) : "v"(p) : "memory");
  return d;
}
// device-coherent 8B store of 4 fp16
__device__ __forceinline__ void store_h4(u16* p, const float* hv) {
  union { u64 q; _Float16 h[4]; } u;
  u.h[0] = (_Float16)hv[0]; u.h[1] = (_Float16)hv[1];
  u.h[2] = (_Float16)hv[2]; u.h[3] = (_Float16)hv[3];
  __hip_atomic_store((u64*)p, u.q, __ATOMIC_RELAXED, __HIP_MEMORY_SCOPE_AGENT);
}

// group-local poll: lanes 0..15 check fA[lane&7] >= nA, lanes 16..31 fB[lane-16] >= nB
__device__ __forceinline__ void poll(const int* fgrp, int lane, int nA, int nB) {
  const int idx = lane & 31;
  const int* p = fgrp + ((idx < 16) ? (idx & 7) : idx);
  const int need = (idx < 16) ? nA : nB;
  for (;;) {
    int v = __hip_atomic_load(p, __ATOMIC_RELAXED, __HIP_MEMORY_SCOPE_AGENT);
    if (__all(v >= need)) break;
  }
  asm volatile("" ::: "memory");
}

// ---------- prep: weight permute+convert, bias sum, zero h, reset flags ----------
__global__ void k_prep(const float* __restrict__ Wih, const float* __restrict__ Whh,
                       const float* __restrict__ bih, const float* __restrict__ bhh,
                       u16* __restrict__ W0p, u16* __restrict__ W1p,
                       float* __restrict__ b1, u16* __restrict__ hz, int* __restrict__ flags)
{
  int i = blockIdx.x * blockDim.x + threadIdx.x;
  int st = gridDim.x * blockDim.x;
  // W0p[wgi][wv][g][m][k] <- Whh0[g*512 + (wgi*4+wv)*16 + m][k]
  for (int e = i; e < 8*4*4*16*512; e += st) {
    int k = e & 511, m = (e >> 9) & 15, g = (e >> 13) & 3, wv = (e >> 15) & 3, wgi = e >> 17;
    int row = g*512 + (wgi*4 + wv)*16 + m;
    W0p[e] = f2h(Whh[row*512 + k]);
  }
  // W1p[wgi][ch][kh][g][m][k] <- (kh?Whh1:Wih1)[g*512 + wgi*32 + ch*16 + m][k]
  for (int e = i; e < 16*2*2*4*16*512; e += st) {
    int k = e & 511, m = (e >> 9) & 15, g = (e >> 13) & 3, kh = (e >> 15) & 1,
        ch = (e >> 16) & 1, wgi = e >> 17;
    int row = g*512 + wgi*32 + ch*16 + m;
    const float* src = kh ? Whh : Wih;
    W1p[e] = f2h(src[2048*512 + row*512 + k]);
  }
  for (int e = i; e < 4*512; e += st) b1[e] = bih[2048 + e] + bhh[2048 + e];
  for (int e = i; e < (NB0 + NB1)*HS; e += st) hz[e] = 0;  // h0 bufs + h1 bufs contiguous
  for (int e = i; e < NGRP*32; e += st) flags[e] = 0;
}

// ---------- pidx: pair index per (t,b), int32/int64 auto-detect ----------
__global__ void k_pidx(const int* __restrict__ inp32, u8* __restrict__ pidx)
{
  __shared__ int is64s;
  if (threadIdx.x == 0) {
    int z = 0;
    for (int t = 0; t < 64; ++t) z |= inp32[2*t + 1];
    is64s = (z == 0) ? 1 : 0;
  }
  __syncthreads();
  const int is64 = is64s;
  int i = blockIdx.x * blockDim.x + threadIdx.x;
  int st = gridDim.x * blockDim.x;
  for (int e = i; e < S_LEN*64; e += st) {
    int t = e >> 6, b = e & 63;
    int i0 = b * S_LEN + t;
    int i1 = 64 * S_LEN + b * S_LEN + t;
    int a = is64 ? inp32[2*i0] : inp32[i0];
    int c = is64 ? inp32[2*i1] : inp32[i1];
    pidx[e] = (u8)(a * 4 + c);
  }
}

// ---------- table: T0[p][g*512+j] = (embed[a]+embed[c]) . Wih0[g*512+j] + bias0 ----------
__global__ void k_table(const float* __restrict__ embed, const float* __restrict__ Wih,
                        const float* __restrict__ bih, const float* __restrict__ bhh,
                        float* __restrict__ T0)
{
  int idx = blockIdx.x * blockDim.x + threadIdx.x;
  if (idx >= 16*2048) return;
  int p = idx >> 11, gj = idx & 2047;
  const float* ea = embed + (p >> 2) * 512;
  const float* ec = embed + (p & 3) * 512;
  const float* w  = Wih + gj * 512;
  float acc = bih[gj] + bhh[gj];
  for (int k = 0; k < 512; ++k) acc += (ea[k] + ec[k]) * w[k];
  T0[p * 2048 + gj] = acc;
}

// ---------- persistent 2-layer LSTM: 4 batch groups, flag-synced, LDS-staged h ----------
__global__ __launch_bounds__(256, 1) void k_lstm(
    const u16* __restrict__ W0p, const u16* __restrict__ W1p,
    const float* __restrict__ T0, const float* __restrict__ b1,
    const u8* __restrict__ pidx,
    u16* __restrict__ h0b, u16* __restrict__ h1b, int* __restrict__ flags)
{
  __shared__ __align__(16) u8 smem[40960];   // staging (16/32KB) + xbuf (8KB @32768)
  const int tid  = threadIdx.x;
  const int lane = tid & 63, wave = tid >> 6;
  const int wg   = blockIdx.x;
  const int mrow = lane & 15;
  const int m4   = (lane >> 4) * 4;
  const int q16  = (lane >> 4) * 16;          // byte offset of k-fragment within 64B
  const int swm  = (mrow & 7) << 4;           // read-side swizzle

  if (wg < 32) {
    // ===== layer 0: group grp; wave owns 16 cols x 4 gates, K=512 =====
    const int grp = wg >> 3, wgi = wg & 7;
    int* fgrp = flags + grp*32;
    const int jc = (wgi*4 + wave) * 16;
    const u16* wbase = W0p + (wgi*4 + wave) * 32768;
    half8 wa[4][16];
#pragma unroll
    for (int g = 0; g < 4; ++g)
#pragma unroll
      for (int ks = 0; ks < 16; ++ks)
        wa[g][ks] = *(const half8*)(wbase + (g*16 + mrow)*512 + ks*32 + (lane >> 4)*8);
    const int bg = grp*16 + mrow;   // global batch row
    // staging role for this thread
    const int sr  = tid >> 4;               // LDS row 0..15
    const int skb = (tid & 15) * 64;        // 64B chunk base within row
    const int ssw = (sr & 7) << 4;
    float cs[4] = {0.f, 0.f, 0.f, 0.f};
    // prefetch t=0 gate-table values
    int p = pidx[bg];
    f32x4 tg[4];
#pragma unroll
    for (int g = 0; g < 4; ++g) tg[g] = *(const f32x4*)(T0 + p*2048 + jc + m4 + g*512);
    for (int t = 0; t < S_LEN; ++t) {
      poll(fgrp, lane, t, t - (NB0 - 1));
      const u16* hr = h0b + ((t + NB0 - 1) % NB0) * HS;   // h0[t-1]
      u16*       hw = h0b + (t % NB0) * HS;               // h0[t]
      // ---- cooperative staged load: 16KB (rows grp*16..+16) -> LDS, swizzled ----
      {
        const char* gs = (const char*)(hr + grp*16*512) + sr*1024 + skb;
        u32x4 d0 = gload16(gs);
        u32x4 d1 = gload16(gs + 16);
        u32x4 d2 = gload16(gs + 32);
        u32x4 d3 = gload16(gs + 48);
        asm volatile("s_waitcnt vmcnt(0)" ::: "memory");
        __builtin_amdgcn_sched_barrier(0);
        *(u32x4*)(smem + sr*1024 + ((skb +  0) ^ ssw)) = d0;
        *(u32x4*)(smem + sr*1024 + ((skb + 16) ^ ssw)) = d1;
        *(u32x4*)(smem + sr*1024 + ((skb + 32) ^ ssw)) = d2;
        *(u32x4*)(smem + sr*1024 + ((skb + 48) ^ ssw)) = d3;
      }
      __syncthreads();
      half8 bf[16];
#pragma unroll
      for (int ks = 0; ks < 16; ++ks)
        bf[ks] = *(const half8*)(smem + mrow*1024 + ((ks*64 + q16) ^ swm));
      f32x4 acc[4] = {{0,0,0,0},{0,0,0,0},{0,0,0,0},{0,0,0,0}};
#pragma unroll
      for (int ks = 0; ks < 16; ++ks)
#pragma unroll
        for (int g = 0; g < 4; ++g)
          acc[g] = MFMA16(wa[g][ks], bf[ks], acc[g]);
      float hv[4];
#pragma unroll
      for (int r = 0; r < 4; ++r) {
        float gi = acc[0][r] + tg[0][r];
        float gf = acc[1][r] + tg[1][r];
        float gg = acc[2][r] + tg[2][r];
        float go = acc[3][r] + tg[3][r];
        float cc = sigf(gf)*cs[r] + sigf(gi)*tanhf_(gg);
        cs[r] = cc;
        hv[r] = sigf(go)*tanhf_(cc);
      }
      store_h4(hw + bg*512 + jc + m4, hv);
      // prefetch next step's table values (off critical path)
      if (t + 1 < S_LEN) {
        int pn = pidx[(t+1)*64 + bg];
#pragma unroll
        for (int g = 0; g < 4; ++g)
          tg[g] = *(const f32x4*)(T0 + pn*2048 + jc + m4 + g*512);
      }
      asm volatile("s_waitcnt vmcnt(0)" ::: "memory");
      __syncthreads();
      if (tid == 0)
        __hip_atomic_store(fgrp + wgi, t + 1, __ATOMIC_RELAXED, __HIP_MEMORY_SCOPE_AGENT);
      // loop-carried pin: weights stay resident on-chip
#pragma unroll
      for (int g = 0; g < 4; ++g)
#pragma unroll
        for (int ks = 0; ks < 16; ++ks)
          asm volatile("" : "+v"(wa[g][ks]));
    }
  } else {
    // ===== layer 1: wave = (ch, kh); 16 cols x 4 gates, K-half 512 (kh0:h0, kh1:h1) =====
    const int w1 = wg - 32;
    const int grp = w1 >> 4, wgi = w1 & 15;
    int* fgrp = flags + grp*32;
    const int kh = wave & 1, ch = wave >> 1;
    const int jc = wgi*32 + ch*16;
    const u16* wbase = W1p + ((wgi*2 + ch)*2 + kh) * 32768;
    half8 wa[4][16];
#pragma unroll
    for (int g = 0; g < 4; ++g)
#pragma unroll
      for (int ks = 0; ks < 16; ++ks)
        wa[g][ks] = *(const half8*)(wbase + (g*16 + mrow)*512 + ks*32 + (lane >> 4)*8);
    const int bg = grp*16 + mrow;
    f32x4* xbuf = (f32x4*)(smem + 32768);
    f32x4 big[4];
#pragma unroll
    for (int g = 0; g < 4; ++g) big[g] = *(const f32x4*)(b1 + g*512 + jc + m4);
    // staging role: threads 0..127 -> h0 region, 128..255 -> h1 region; 128B each
    const int shalf = tid >> 7;
    const int sidx  = tid & 127;
    const int sr    = sidx >> 3;
    const int skb   = (sidx & 7) * 128;
    const int ssw   = (sr & 7) << 4;
    char* ls = (char*)smem + shalf*16384;
    float cs[4] = {0.f, 0.f, 0.f, 0.f};
    for (int w = 1; w <= S_LEN; ++w) {
      const int u = w - 1;   // computing h1[u]
      poll(fgrp, lane, w, w - 1);
      const u16* h0s = h0b + (u % NB0) * HS;               // h0[u]
      const u16* h1s = h1b + ((u + NB1 - 1) % NB1) * HS;   // h1[u-1]
      u16* hw = h1b + (u % NB1) * HS;                      // h1[u]
      // ---- cooperative staged load: h0 16KB + h1 16KB -> LDS, swizzled ----
      {
        const u16* gsrc = shalf ? h1s : h0s;
        const char* gs = (const char*)(gsrc + grp*16*512) + sr*1024 + skb;
        u32x4 d0 = gload16(gs);
        u32x4 d1 = gload16(gs + 16);
        u32x4 d2 = gload16(gs + 32);
        u32x4 d3 = gload16(gs + 48);
        u32x4 d4 = gload16(gs + 64);
        u32x4 d5 = gload16(gs + 80);
        u32x4 d6 = gload16(gs + 96);
        u32x4 d7 = gload16(gs + 112);
        asm volatile("s_waitcnt vmcnt(0)" ::: "memory");
        __builtin_amdgcn_sched_barrier(0);
        *(u32x4*)(ls + sr*1024 + ((skb +   0) ^ ssw)) = d0;
        *(u32x4*)(ls + sr*1024 + ((skb +  16) ^ ssw)) = d1;
        *(u32x4*)(ls + sr*1024 + ((skb +  32) ^ ssw)) = d2;
        *(u32x4*)(ls + sr*1024 + ((skb +  48) ^ ssw)) = d3;
        *(u32x4*)(ls + sr*1024 + ((skb +  64) ^ ssw)) = d4;
        *(u32x4*)(ls + sr*1024 + ((skb +  80) ^ ssw)) = d5;
        *(u32x4*)(ls + sr*1024 + ((skb +  96) ^ ssw)) = d6;
        *(u32x4*)(ls + sr*1024 + ((skb + 112) ^ ssw)) = d7;
      }
      __syncthreads();
      const char* lsrc = (const char*)smem + kh*16384;
      half8 bf[16];
#pragma unroll
      for (int ks = 0; ks < 16; ++ks)
        bf[ks] = *(const half8*)(lsrc + mrow*1024 + ((ks*64 + q16) ^ swm));
      f32x4 acc[4] = {{0,0,0,0},{0,0,0,0},{0,0,0,0},{0,0,0,0}};
#pragma unroll
      for (int ks = 0; ks < 16; ++ks)
#pragma unroll
        for (int g = 0; g < 4; ++g)
          acc[g] = MFMA16(wa[g][ks], bf[ks], acc[g]);
      if (kh == 1) {
#pragma unroll
        for (int g = 0; g < 4; ++g)
          xbuf[(ch*4 + g)*64 + lane] = acc[g];
      }
      __syncthreads();
      if (kh == 0) {
#pragma unroll
        for (int g = 0; g < 4; ++g)
          acc[g] += xbuf[(ch*4 + g)*64 + lane];
        float hv[4];
#pragma unroll
        for (int r = 0; r < 4; ++r) {
          float gi = acc[0][r] + big[0][r];
          float gf = acc[1][r] + big[1][r];
          float gg = acc[2][r] + big[2][r];
          float go = acc[3][r] + big[3][r];
          float cc = sigf(gf)*cs[r] + sigf(gi)*tanhf_(gg);
          cs[r] = cc;
          hv[r] = sigf(go)*tanhf_(cc);
        }
        store_h4(hw + bg*512 + jc + m4, hv);
      }
      asm volatile("s_waitcnt vmcnt(0)" ::: "memory");
      __syncthreads();
      if (tid == 0)
        __hip_atomic_store(fgrp + 16 + wgi, w, __ATOMIC_RELAXED, __HIP_MEMORY_SCOPE_AGENT);
#pragma unroll
      for (int g = 0; g < 4; ++g)
#pragma unroll
        for (int ks = 0; ks < 16; ++ks)
          asm volatile("" : "+v"(wa[g][ks]));
    }
  }
}

// ---------- finalize: LayerNorm + projection from h1[2047] (fp16) ----------
__global__ __launch_bounds__(256) void k_final(
    const u16* __restrict__ h1last, const float* __restrict__ ln_g,
    const float* __restrict__ ln_b, const float* __restrict__ Wp,
    const float* __restrict__ bp, float* __restrict__ out)
{
  __shared__ float sb[8];
  __shared__ float sred[4];
  const int b = blockIdx.x, tid = threadIdx.x;
  const _Float16* h = (const _Float16*)(h1last) + b * 512;
  float v1 = (float)h[tid], v2 = (float)h[tid + 256];
  float s1 = v1 + v2, s2 = v1*v1 + v2*v2;
#pragma unroll
  for (int o = 32; o; o >>= 1) { s1 += __shfl_down(s1, o); s2 += __shfl_down(s2, o); }
  if ((tid & 63) == 0) { sb[tid >> 6] = s1; sb[4 + (tid >> 6)] = s2; }
  __syncthreads();
  float S1 = sb[0] + sb[1] + sb[2] + sb[3];
  float S2 = sb[4] + sb[5] + sb[6] + sb[7];
  float mu = S1 * (1.f/512.f);
  float var = S2 * (1.f/512.f) - mu*mu;
  float inv = rsqrtf(var + 1e-5f);
  float acc = ((v1 - mu)*inv*ln_g[tid]       + ln_b[tid])       * Wp[tid]
            + ((v2 - mu)*inv*ln_g[tid + 256] + ln_b[tid + 256]) * Wp[tid + 256];
#pragma unroll
  for (int o = 32; o; o >>= 1) acc += __shfl_down(acc, o);
  if ((tid & 63) == 0) sred[tid >> 6] = acc;
  __syncthreads();
  if (tid == 0) out[b] = sred[0] + sred[1] + sred[2] + sred[3] + bp[0];
}

extern "C" void kernel_launch(void* const* d_in, const int* in_sizes, int n_in,
                              void* d_out, int out_size, void* d_ws, size_t ws_size,
                              hipStream_t stream) {
  (void)in_sizes; (void)n_in; (void)out_size; (void)ws_size;
  const int*   inp   = (const int*)d_in[0];
  const float* embed = (const float*)d_in[1];
  const float* Wih   = (const float*)d_in[2];
  const float* Whh   = (const float*)d_in[3];
  const float* bih   = (const float*)d_in[4];
  const float* bhh   = (const float*)d_in[5];
  const float* ln_g  = (const float*)d_in[6];
  const float* ln_b  = (const float*)d_in[7];
  const float* Wp    = (const float*)d_in[8];
  const float* bp    = (const float*)d_in[9];
  float* out = (float*)d_out;
  char* ws = (char*)d_ws;

  u16*   W0p  = (u16*)  (ws + OFF_W0P);
  u16*   W1p  = (u16*)  (ws + OFF_W1P);
  float* T0   = (float*)(ws + OFF_T0);
  float* b1   = (float*)(ws + OFF_B1);
  u8*    pidx = (u8*)   (ws + OFF_PIDX);
  u16*   h0   = (u16*)  (ws + OFF_H0);
  u16*   h1   = (u16*)  (ws + OFF_H1);
  int*   flags= (int*)  (ws + OFF_FLAG);

  k_prep<<<512, 256, 0, stream>>>(Wih, Whh, bih, bhh, W0p, W1p, b1, h0, flags);
  k_pidx<<<64, 256, 0, stream>>>(inp, pidx);
  k_table<<<128, 256, 0, stream>>>(embed, Wih, bih, bhh, T0);

  k_lstm<<<dim3(96), dim3(256), 0, stream>>>(W0p, W1p, T0, b1, pidx, h0, h1, flags);

  // h1[2047] lives in buffer (2047 % 4) == 3
  k_final<<<64, 256, 0, stream>>>(h1 + 3*HS, ln_g, ln_b, Wp, bp, out);
}